// Round 5
// baseline (71.140 us; speedup 1.0000x reference)
//
#include <hip/hip_runtime.h>

#define GDIM 38
#define GG   (GDIM * GDIM)          // 1444
#define TOTAL (GDIM * GDIM * GDIM)  // 54872

// 13 half-shell displacements (buckets_per_cutoff == 1), matches VEC_DISP
__device__ __constant__ int c_disp[13][3] = {
    {-1, 0, 0}, {-1, -1, 0}, {0, -1, 0}, {1, -1, 0},
    {-1, 1, -1}, {0, 1, -1}, {1, 1, -1}, {-1, 0, -1},
    {0, 0, -1}, {1, 0, -1}, {-1, -1, -1}, {0, -1, -1}, {1, -1, -1}};

// translation-case LUT indexed by cx*9+cy*3+cz, cat: 0=low(0), 1=mid, 2=high(G+1)
__device__ __constant__ unsigned char c_case[27] = {
    11,  2, 0,   8,  1, 0,   5, 14, 0,
    12,  3, 0,   9,  0, 0,   6, 15, 0,
    13,  4, 0,  10, 17, 0,   7, 16, 0};

#define BS 256
// LDS float4 layout: [0,192)=frac/coords, [192,1024)=nf, [1024,1856)=nc
#define F4_FRAC 0
#define F4_NF   192
#define F4_NC   1024

__global__ __launch_bounds__(BS) void cell_atoms_kernel(
    const float* __restrict__ coords, const float* __restrict__ cell,
    float* __restrict__ out, int* __restrict__ cnt, int N)
{
    __shared__ float4 s4[1856];              // 29.7 KB
    float* s = (float*)s4;

    const int tid = threadIdx.x;
    const long long blockbase = (long long)blockIdx.x * BS;
    const int valid = (int)min((long long)BS, (long long)N - blockbase);
    const bool full = (valid == BS);
    const bool i_ok = tid < valid;

    const long long OFF0 = 0;            // frac       (3N)
    const long long OFF1 = 3LL * N;      // flat index (N)
    const long long OFF2 = 4LL * N;      // neigh flat (13N)
    const long long OFF3 = 17LL * N;     // neigh case (13N)

    // ---- coalesced coord load into LDS ----
    if (full) {
        const float4* src = (const float4*)(coords + blockbase * 3);
        if (tid < 192) s4[F4_FRAC + tid] = src[tid];
    } else {
        const float* src = coords + blockbase * 3;
        for (int j = tid; j < valid * 3; j += BS) s[j] = src[j];
    }
    __syncthreads();

    // ---- per-atom compute; frac overwrites own coords in place (no barrier
    //      needed: thread t reads/writes only s[3t..3t+2]) ----
    int v[3];
    if (i_ok) {
#pragma unroll
        for (int a = 0; a < 3; ++a) {
            float d = cell[4 * a];              // diagonal
            float f = s[3 * tid + a] / d;       // IEEE divide, matches jnp
            f = f - floorf(f);
            if (f >= 1.0f) f -= 1.0f;
            if (f < 0.0f)  f += 1.0f;
            s[3 * tid + a] = f;
            v[a] = (int)floorf(f * (float)GDIM);
        }

        // flat index (coalesced direct store) + histogram
        int flat = v[0] * GG + v[1] * GDIM + v[2];
        out[OFF1 + blockbase + tid] = (float)flat;
        atomicAdd(&cnt[flat], 1);

        // neighbor flat + case → staged into LDS
#pragma unroll
        for (int k = 0; k < 13; ++k) {
            int cidx = 0, f2 = 0;
#pragma unroll
            for (int a = 0; a < 3; ++a) {
                int n = v[a] + 1 + c_disp[k][a];   // padded coord, [0, G+1]
                int cat = (n == 0) ? 0 : ((n == GDIM + 1) ? 2 : 1);
                int m = (n == 0) ? (GDIM - 1) : ((n == GDIM + 1) ? 0 : n - 1);
                cidx = cidx * 3 + cat;
                f2 += m * (a == 0 ? GG : (a == 1 ? GDIM : 1));
            }
            s[4 * F4_NF + 13 * tid + k] = (float)f2;           // stride 13: 2-way = free
            s[4 * F4_NC + 13 * tid + k] = (float)c_case[cidx];
        }
    }
    __syncthreads();

    // ---- single drain: frac, nf, nc as float4 ----
    if (full) {
        float4* dfrac = (float4*)(out + OFF0 + blockbase * 3);
        if (tid < 192) dfrac[tid] = s4[F4_FRAC + tid];

        float4* dnf = (float4*)(out + OFF2 + blockbase * 13);
        float4* dnc = (float4*)(out + OFF3 + blockbase * 13);
#pragma unroll
        for (int j = tid; j < 832; j += BS) {
            dnf[j] = s4[F4_NF + j];
            dnc[j] = s4[F4_NC + j];
        }
    } else {
        float* dfrac = out + OFF0 + blockbase * 3;
        for (int j = tid; j < valid * 3; j += BS) dfrac[j] = s[j];
        float* dnf = out + OFF2 + blockbase * 13;
        float* dnc = out + OFF3 + blockbase * 13;
        for (int j = tid; j < valid * 13; j += BS) {
            dnf[j] = s[4 * F4_NF + j];
            dnc[j] = s[4 * F4_NC + j];
        }
    }
}

__global__ __launch_bounds__(1024) void zero_kernel(int4* __restrict__ p, int n4)
{
    int i = blockIdx.x * 1024 + threadIdx.x;
    if (i < n4) p[i] = make_int4(0, 0, 0, 0);
}

// Parallel scan: 54 blocks; each block sums everything before its range
// (L2-resident, coalesced) and block-scans its own 1024 counts.
__global__ __launch_bounds__(1024) void scan_kernel(
    const int* __restrict__ cnt,
    float* __restrict__ out_count,
    float* __restrict__ out_cum)
{
    __shared__ int lds[1024];
    const int t = threadIdx.x;
    const int base = blockIdx.x * 1024;

    // 1) prefix base = sum of cnt[0..base)  (coalesced, L2-hit)
    int pre = 0;
    for (int j = t; j < base; j += 1024) pre += cnt[j];
    lds[t] = pre;
    __syncthreads();
    for (int off = 512; off > 0; off >>= 1) {
        if (t < off) lds[t] += lds[t + off];
        __syncthreads();
    }
    const int blockpre = lds[0];
    __syncthreads();

    // 2) own element
    const int idx = base + t;
    const int c = (idx < TOTAL) ? cnt[idx] : 0;

    // 3) intra-block inclusive scan (Hillis–Steele)
    lds[t] = c;
    __syncthreads();
    for (int off = 1; off < 1024; off <<= 1) {
        int vprev = (t >= off) ? lds[t - off] : 0;
        __syncthreads();
        lds[t] += vprev;
        __syncthreads();
    }
    const int exc = lds[t] - c;

    if (idx < TOTAL) {
        out_count[idx] = (float)c;
        out_cum[idx]   = (float)(blockpre + exc);
    }
}

extern "C" void kernel_launch(void* const* d_in, const int* in_sizes, int n_in,
                              void* d_out, int out_size, void* d_ws, size_t ws_size,
                              hipStream_t stream)
{
    const float* coords = (const float*)d_in[0];
    const float* cell   = (const float*)d_in[1];
    float* out = (float*)d_out;
    int* cnt = (int*)d_ws;

    // out_size = 30N + 2*TOTAL
    int N = (int)((out_size - 2 * TOTAL) / 30);

    const int n4 = TOTAL / 4;  // 54872 % 4 == 0 -> 13718 int4
    zero_kernel<<<(n4 + 1023) / 1024, 1024, 0, stream>>>((int4*)cnt, n4);

    cell_atoms_kernel<<<(N + BS - 1) / BS, BS, 0, stream>>>(coords, cell, out, cnt, N);

    long long off4 = 30LL * N;  // count then cumcount at the tail
    scan_kernel<<<(TOTAL + 1023) / 1024, 1024, 0, stream>>>(
        cnt, out + off4, out + off4 + TOTAL);
}

// Round 7
// 70.386 us; speedup vs baseline: 1.0107x; 1.0107x over previous
//
#include <hip/hip_runtime.h>

#define GDIM 38
#define GG   (GDIM * GDIM)          // 1444
#define TOTAL (GDIM * GDIM * GDIM)  // 54872

typedef float f32x4 __attribute__((ext_vector_type(4)));

// 13 half-shell displacements (buckets_per_cutoff == 1), matches VEC_DISP
__device__ __constant__ int c_disp[13][3] = {
    {-1, 0, 0}, {-1, -1, 0}, {0, -1, 0}, {1, -1, 0},
    {-1, 1, -1}, {0, 1, -1}, {1, 1, -1}, {-1, 0, -1},
    {0, 0, -1}, {1, 0, -1}, {-1, -1, -1}, {0, -1, -1}, {1, -1, -1}};

// translation-case LUT indexed by cx*9+cy*3+cz, cat: 0=low(0), 1=mid, 2=high(G+1)
__device__ __constant__ unsigned char c_case[27] = {
    11,  2, 0,   8,  1, 0,   5, 14, 0,
    12,  3, 0,   9,  0, 0,   6, 15, 0,
    13,  4, 0,  10, 17, 0,   7, 16, 0};

#define BS 256
// LDS f32x4 layout: [0,192)=frac/coords, [192,1024)=nf, [1024,1856)=nc
#define F4_FRAC 0
#define F4_NF   192
#define F4_NC   1024

__global__ __launch_bounds__(BS) void cell_atoms_kernel(
    const float* __restrict__ coords, const float* __restrict__ cell,
    float* __restrict__ out, int* __restrict__ cnt, int N)
{
    __shared__ f32x4 s4[1856];               // 29.7 KB
    float* s = (float*)s4;

    const int tid = threadIdx.x;
    const long long blockbase = (long long)blockIdx.x * BS;
    const int valid = (int)min((long long)BS, (long long)N - blockbase);
    const bool full = (valid == BS);
    const bool i_ok = tid < valid;

    const long long OFF0 = 0;            // frac       (3N)
    const long long OFF1 = 3LL * N;      // flat index (N)
    const long long OFF2 = 4LL * N;      // neigh flat (13N)
    const long long OFF3 = 17LL * N;     // neigh case (13N)

    // ---- coalesced coord load into LDS ----
    if (full) {
        const f32x4* src = (const f32x4*)(coords + blockbase * 3);
        if (tid < 192) s4[F4_FRAC + tid] = src[tid];
    } else {
        const float* src = coords + blockbase * 3;
        for (int j = tid; j < valid * 3; j += BS) s[j] = src[j];
    }
    __syncthreads();

    // ---- per-atom compute; frac overwrites own coords in place (no barrier
    //      needed: thread t reads/writes only s[3t..3t+2]) ----
    int v[3];
    if (i_ok) {
#pragma unroll
        for (int a = 0; a < 3; ++a) {
            float d = cell[4 * a];              // diagonal
            float f = s[3 * tid + a] / d;       // IEEE divide, matches jnp
            f = f - floorf(f);
            if (f >= 1.0f) f -= 1.0f;
            if (f < 0.0f)  f += 1.0f;
            s[3 * tid + a] = f;
            v[a] = (int)floorf(f * (float)GDIM);
        }

        // flat index (coalesced direct nt store) + histogram
        int flat = v[0] * GG + v[1] * GDIM + v[2];
        __builtin_nontemporal_store((float)flat, &out[OFF1 + blockbase + tid]);
        atomicAdd(&cnt[flat], 1);

        // neighbor flat + case → staged into LDS
#pragma unroll
        for (int k = 0; k < 13; ++k) {
            int cidx = 0, f2 = 0;
#pragma unroll
            for (int a = 0; a < 3; ++a) {
                int n = v[a] + 1 + c_disp[k][a];   // padded coord, [0, G+1]
                int cat = (n == 0) ? 0 : ((n == GDIM + 1) ? 2 : 1);
                int m = (n == 0) ? (GDIM - 1) : ((n == GDIM + 1) ? 0 : n - 1);
                cidx = cidx * 3 + cat;
                f2 += m * (a == 0 ? GG : (a == 1 ? GDIM : 1));
            }
            s[4 * F4_NF + 13 * tid + k] = (float)f2;           // stride 13: 2-way = free
            s[4 * F4_NC + 13 * tid + k] = (float)c_case[cidx];
        }
    }
    __syncthreads();

    // ---- single drain: frac, nf, nc as nontemporal f32x4 ----
    if (full) {
        f32x4* dfrac = (f32x4*)(out + OFF0 + blockbase * 3);
        if (tid < 192) __builtin_nontemporal_store(s4[F4_FRAC + tid], &dfrac[tid]);

        f32x4* dnf = (f32x4*)(out + OFF2 + blockbase * 13);
        f32x4* dnc = (f32x4*)(out + OFF3 + blockbase * 13);
#pragma unroll
        for (int j = tid; j < 832; j += BS) {
            __builtin_nontemporal_store(s4[F4_NF + j], &dnf[j]);
            __builtin_nontemporal_store(s4[F4_NC + j], &dnc[j]);
        }
    } else {
        float* dfrac = out + OFF0 + blockbase * 3;
        for (int j = tid; j < valid * 3; j += BS)
            __builtin_nontemporal_store(s[j], &dfrac[j]);
        float* dnf = out + OFF2 + blockbase * 13;
        float* dnc = out + OFF3 + blockbase * 13;
        for (int j = tid; j < valid * 13; j += BS) {
            __builtin_nontemporal_store(s[4 * F4_NF + j], &dnf[j]);
            __builtin_nontemporal_store(s[4 * F4_NC + j], &dnc[j]);
        }
    }
}

__global__ __launch_bounds__(1024) void zero_kernel(int4* __restrict__ p, int n4)
{
    int i = blockIdx.x * 1024 + threadIdx.x;
    if (i < n4) p[i] = make_int4(0, 0, 0, 0);
}

// Parallel scan: 54 blocks; each block sums everything before its range
// (L2-resident, coalesced) and block-scans its own 1024 counts.
__global__ __launch_bounds__(1024) void scan_kernel(
    const int* __restrict__ cnt,
    float* __restrict__ out_count,
    float* __restrict__ out_cum)
{
    __shared__ int lds[1024];
    const int t = threadIdx.x;
    const int base = blockIdx.x * 1024;

    // 1) prefix base = sum of cnt[0..base)  (coalesced, L2-hit)
    int pre = 0;
    for (int j = t; j < base; j += 1024) pre += cnt[j];
    lds[t] = pre;
    __syncthreads();
    for (int off = 512; off > 0; off >>= 1) {
        if (t < off) lds[t] += lds[t + off];
        __syncthreads();
    }
    const int blockpre = lds[0];
    __syncthreads();

    // 2) own element
    const int idx = base + t;
    const int c = (idx < TOTAL) ? cnt[idx] : 0;

    // 3) intra-block inclusive scan (Hillis–Steele)
    lds[t] = c;
    __syncthreads();
    for (int off = 1; off < 1024; off <<= 1) {
        int vprev = (t >= off) ? lds[t - off] : 0;
        __syncthreads();
        lds[t] += vprev;
        __syncthreads();
    }
    const int exc = lds[t] - c;

    if (idx < TOTAL) {
        __builtin_nontemporal_store((float)c, &out_count[idx]);
        __builtin_nontemporal_store((float)(blockpre + exc), &out_cum[idx]);
    }
}

extern "C" void kernel_launch(void* const* d_in, const int* in_sizes, int n_in,
                              void* d_out, int out_size, void* d_ws, size_t ws_size,
                              hipStream_t stream)
{
    const float* coords = (const float*)d_in[0];
    const float* cell   = (const float*)d_in[1];
    float* out = (float*)d_out;
    int* cnt = (int*)d_ws;

    // out_size = 30N + 2*TOTAL
    int N = (int)((out_size - 2 * TOTAL) / 30);

    const int n4 = TOTAL / 4;  // 54872 % 4 == 0 -> 13718 int4
    zero_kernel<<<(n4 + 1023) / 1024, 1024, 0, stream>>>((int4*)cnt, n4);

    cell_atoms_kernel<<<(N + BS - 1) / BS, BS, 0, stream>>>(coords, cell, out, cnt, N);

    long long off4 = 30LL * N;  // count then cumcount at the tail
    scan_kernel<<<(TOTAL + 1023) / 1024, 1024, 0, stream>>>(
        cnt, out + off4, out + off4 + TOTAL);
}